// Round 19
// baseline (140.896 us; speedup 1.0000x reference)
//
#include <hip/hip_runtime.h>
#include <stddef.h>

// Output layout (fp32):
//   recon    [200,4096,64] @ 0
//   z0_mean  [4096,3]      @ 52428800
//   z0_logvar[4096,3]      @ 52441088
//   traj     [200,4096,3]  @ 52453376
#define OFF_MEAN 52428800
#define OFF_LV   52441088
#define OFF_TRAJ 52453376

typedef _Float16 f16x8 __attribute__((ext_vector_type(8)));
typedef _Float16 f16x4 __attribute__((ext_vector_type(4)));
typedef _Float16 f16x2 __attribute__((ext_vector_type(2)));
typedef float    f32x4 __attribute__((ext_vector_type(4)));

#define MFMA16(a, b, c) __builtin_amdgcn_mfma_f32_16x16x32_f16((a), (b), (c), 0, 0, 0)

// fast transcendentals: v_exp_f32 + v_rcp_f32 (error ~1e-6, far below budget)
__device__ __forceinline__ float sigm_(float x) {
    float e = __builtin_amdgcn_exp2f(x * -1.442695041f);
    return __builtin_amdgcn_rcpf(1.f + e);
}
__device__ __forceinline__ float tanh_(float x) {
    float e = __builtin_amdgcn_exp2f(x * 2.885390082f);
    return 1.f - 2.f * __builtin_amdgcn_rcpf(e + 1.f);
}
__device__ __forceinline__ float dot4_(float4 a, float4 b) {
    return a.x * b.x + a.y * b.y + a.z * b.z + a.w * b.w;
}

// ---------------------------------------------------------------- GRU (MFMA, gate-aligned, single-f16)
// (round-9 version: 256 blocks x 512 threads, 16 rows/block — full-density MFMA tiles)
__global__ __launch_bounds__(512, 2) void k_gru(
    const float* __restrict__ obs, const float* __restrict__ eps,
    const float* __restrict__ Wih, const float* __restrict__ Whh,
    const float* __restrict__ bih, const float* __restrict__ bhh,
    const float* __restrict__ meanW, const float* __restrict__ meanB,
    const float* __restrict__ lvW,  const float* __restrict__ lvB,
    float* __restrict__ o_mean, float* __restrict__ o_lv, float* __restrict__ z0)
{
    __shared__ alignas(16) unsigned short h_s[2][2048];  // [16][128] f16, 4-bit swizzle, dbuf
    __shared__ alignas(16) unsigned short x_s[2][1024];  // [16][64]  f16, 3-bit swizzle, dbuf
    __shared__ alignas(16) float hm_s[16 * 132];
    __shared__ float mb_s[96];

    const int tid  = threadIdx.x;
    const int b0   = blockIdx.x * 16;
    const int lane = tid & 63, wv = tid >> 6;
    const int lrow = lane & 15, lkb = lane >> 4;
    const int swX  = (lrow & 7) << 4;
    const int swH  = lrow << 4;
    const int u    = wv * 16 + lrow;

    const float bR  = bih[u]       + bhh[u];
    const float bZ  = bih[128 + u] + bhh[128 + u];
    const float bNi = bih[256 + u];
    const float bNh = bhh[256 + u];

    f16x8 wihf[3][2];
    #pragma unroll
    for (int g = 0; g < 3; ++g) {
        int col = g * 128 + u;
        #pragma unroll
        for (int ks = 0; ks < 2; ++ks) {
            const float* wp = Wih + col * 64 + ks * 32 + lkb * 8;
            float4 a = *(const float4*)wp, b = *(const float4*)(wp + 4);
            float tmp[8] = {a.x, a.y, a.z, a.w, b.x, b.y, b.z, b.w};
            f16x8 hv;
            #pragma unroll
            for (int j = 0; j < 8; ++j) hv[j] = (_Float16)tmp[j];
            wihf[g][ks] = hv;
        }
    }
    f16x8 whhh[3][4];
    #pragma unroll
    for (int g = 0; g < 3; ++g) {
        int col = g * 128 + u;
        #pragma unroll
        for (int ks = 0; ks < 4; ++ks) {
            const float* wp = Whh + col * 128 + ks * 32 + lkb * 8;
            float4 a = *(const float4*)wp, b = *(const float4*)(wp + 4);
            float tmp[8] = {a.x, a.y, a.z, a.w, b.x, b.y, b.z, b.w};
            f16x8 hv;
            #pragma unroll
            for (int j = 0; j < 8; ++j) hv[j] = (_Float16)tmp[j];
            whhh[g][ks] = hv;
        }
    }

    for (int i = tid; i < 2048; i += 512) h_s[0][i] = 0;
    const int srow = tid >> 4, skq = (tid & 15) * 4;
    const int sxb  = srow * 128 + ((skq * 2) ^ ((srow & 7) << 4));
    float4 xn;
    if (tid < 256) {
        xn = *(const float4*)(obs + ((size_t)0 * 4096 + b0 + srow) * 64 + skq);
        f16x4 vh = {(_Float16)xn.x, (_Float16)xn.y, (_Float16)xn.z, (_Float16)xn.w};
        *(f16x4*)((char*)x_s[0] + sxb) = vh;
    }
    f32x4 hold = {0.f, 0.f, 0.f, 0.f};
    __syncthreads();

    for (int t = 0; t < 50; ++t) {
        const int cur = t & 1, nxt = cur ^ 1;
        char* x_c = (char*)x_s[cur];
        char* h_c = (char*)h_s[cur];

        if (tid < 256) {
            int tt = (t < 49) ? t + 1 : t;
            xn = *(const float4*)(obs + ((size_t)tt * 4096 + b0 + srow) * 64 + skq);
        }

        f16x8 xh[2], hh[4];
        #pragma unroll
        for (int ks = 0; ks < 2; ++ks) {
            int off = lrow * 128 + ((ks * 64 + lkb * 16) ^ swX);
            xh[ks] = *(const f16x8*)(x_c + off);
        }
        #pragma unroll
        for (int ks = 0; ks < 4; ++ks) {
            int off = lrow * 256 + ((ks * 64 + lkb * 16) ^ swH);
            hh[ks] = *(const f16x8*)(h_c + off);
        }

        f32x4 z4 = {0.f, 0.f, 0.f, 0.f};
        f32x4 aR = z4, aZ = z4, aNi = z4, aNh = z4;
        #pragma unroll
        for (int ks = 0; ks < 2; ++ks) {
            aR  = MFMA16(xh[ks], wihf[0][ks], aR);
            aZ  = MFMA16(xh[ks], wihf[1][ks], aZ);
            aNi = MFMA16(xh[ks], wihf[2][ks], aNi);
        }
        #pragma unroll
        for (int ks = 0; ks < 4; ++ks) {
            aR  = MFMA16(hh[ks], whhh[0][ks], aR);
            aZ  = MFMA16(hh[ks], whhh[1][ks], aZ);
            aNh = MFMA16(hh[ks], whhh[2][ks], aNh);
        }

        char* hn_c = (char*)h_s[nxt];
        #pragma unroll
        for (int i = 0; i < 4; ++i) {
            float rg = sigm_(aR[i] + bR);
            float zg = sigm_(aZ[i] + bZ);
            float n  = tanh_(aNi[i] + bNi + rg * (aNh[i] + bNh));
            float hv = (1.f - zg) * n + zg * hold[i];
            hold[i] = hv;
            int ri = lkb * 4 + i;
            int hb = ri * 256 + ((u * 2) ^ (ri << 4));
            *(_Float16*)(hn_c + hb) = (_Float16)hv;
        }

        if (tid < 256 && t < 49) {
            f16x4 vh = {(_Float16)xn.x, (_Float16)xn.y, (_Float16)xn.z, (_Float16)xn.w};
            *(f16x4*)((char*)x_s[nxt] + sxb) = vh;
        }
        __syncthreads();
    }

    #pragma unroll
    for (int i = 0; i < 4; ++i)
        hm_s[(lkb * 4 + i) * 132 + u] = hold[i];
    __syncthreads();

    if (tid < 96) {
        int rr = tid / 6, c = tid - rr * 6, j = (c < 3) ? c : c - 3;
        const float* W = (c < 3) ? meanW : lvW;
        const float* B = (c < 3) ? meanB : lvB;
        float acc = B[j];
        const float4* W4 = (const float4*)(W + j * 128);
        const float4* h4 = (const float4*)(hm_s + rr * 132);
        #pragma unroll 4
        for (int kc = 0; kc < 32; ++kc) acc += dot4_(W4[kc], h4[kc]);
        mb_s[rr * 6 + c] = acc;
    }
    __syncthreads();
    if (tid < 48) {
        int rr = tid / 3, j = tid - rr * 3;
        int gb = b0 + rr;
        float m  = mb_s[rr * 6 + j];
        float lv = mb_s[rr * 6 + j + 3];
        o_mean[gb * 3 + j] = m;
        o_lv[gb * 3 + j]   = lv;
        z0[gb * 3 + j]     = m + eps[gb * 3 + j] * __expf(0.5f * lv);
    }
}

// ---------------------------------------------------------------- ODE + decoder (fused, h=0.25 windows)
// 512 blocks x 256 threads (4 waves), 8 rows/block, 2 blocks/CU.
// RK4: 8 uniform windows h=0.25; each emits 25 dense points (t=25s+q,
// th=0.04q). 33 fevals. Decode of window s-1 rides step s's regions:
// Z@k2, H0(rows 0-127)@k3, {H1(128-191)+H2(192-199)+M tiles0-5}@k4,
// M tiles6-12@f (tile 12 store-guarded pr<200). Epilogue decodes window 7.
__global__ __launch_bounds__(256, 2) void k_odec(
    const float* __restrict__ dW1, const float* __restrict__ db1,
    const float* __restrict__ dW2, const float* __restrict__ db2,
    const float* __restrict__ dW3, const float* __restrict__ db3,
    const float* __restrict__ decW1, const float* __restrict__ decb1,
    const float* __restrict__ decW2, const float* __restrict__ decb2,
    const float* __restrict__ z0, float* __restrict__ traj, float* __restrict__ recon)
{
    __shared__ alignas(16) unsigned short h1_s[2048];    // [16][128] f16 swz (rows 8..15 = 0)
    __shared__ alignas(16) unsigned short hd_s[13312];   // [208][64] f16 swz (rows 200-207 pad)
    __shared__ alignas(16) float h2f[8 * 104];
    __shared__ alignas(16) float W3s[312];
    __shared__ alignas(16) float zbuf[200 * 4];
    __shared__ float w1ds[192], b1ds[64];
    __shared__ float b2s[100], b3s[3];
    __shared__ float fparts[24];

    const int tid  = threadIdx.x;
    const int b0   = blockIdx.x * 8;
    const int lane = tid & 63, wv = tid >> 6;
    const int r    = tid >> 5;
    const int lrow = lane & 15, lkb = lane >> 4;
    const int swA  = (lrow & 7) << 4;
    char* h1c = (char*)h1_s;
    char* hdc = (char*)hd_s;

    // init LDS
    for (int i = tid; i < 512; i += 256)
        ((unsigned int*)(h1c + 2048))[i] = 0u;
    for (int i = tid; i < 256; i += 256)           // zero hd pad rows 200..207
        ((unsigned int*)(hdc + 25600))[i] = 0u;
    if (tid < 32) h2f[(tid >> 2) * 104 + 100 + (tid & 3)] = 0.f;
    for (int i = tid; i < 312; i += 256) {
        int j = i / 104, k = i - j * 104;
        W3s[i] = (k < 100) ? dW3[j * 100 + k] : 0.f;
    }
    if (tid < 100) b2s[tid] = db2[tid];
    if (tid < 3)   b3s[tid] = db3[tid];
    if (tid < 192) w1ds[tid] = decW1[tid];
    if (tid < 64)  b1ds[tid] = decb1[tid];

    float w1r[12], b1r[4];
    {
        int k0q = (tid & 31) * 4;
        #pragma unroll
        for (int i = 0; i < 4; ++i) {
            int k = k0q + i;
            if (k < 100) {
                w1r[3 * i + 0] = dW1[k * 3 + 0];
                w1r[3 * i + 1] = dW1[k * 3 + 1];
                w1r[3 * i + 2] = dW1[k * 3 + 2];
                b1r[i] = db1[k];
            } else {
                w1r[3 * i + 0] = 0.f; w1r[3 * i + 1] = 0.f; w1r[3 * i + 2] = 0.f;
                b1r[i] = 0.f;
            }
        }
    }
    f16x8 w2h[2][4];
    #pragma unroll
    for (int tile = 0; tile < 2; ++tile) {
        int col = (wv * 2 + tile) * 16 + lrow;
        #pragma unroll
        for (int ks = 0; ks < 4; ++ks) {
            f16x8 hv;
            #pragma unroll
            for (int j = 0; j < 8; ++j) {
                int k = ks * 32 + lkb * 8 + j;
                float v = (col < 100 && k < 100) ? dW2[col * 100 + k] : 0.f;
                hv[j] = (_Float16)v;
            }
            w2h[tile][ks] = hv;
        }
    }
    const int colD = wv * 16 + lrow;
    f16x8 dbh[2];
    #pragma unroll
    for (int ks = 0; ks < 2; ++ks) {
        const float* wp = decW2 + colD * 64 + ks * 32 + lkb * 8;
        float4 a = *(const float4*)wp, b = *(const float4*)(wp + 4);
        float tmp[8] = {a.x, a.y, a.z, a.w, b.x, b.y, b.z, b.w};
        f16x8 hv;
        #pragma unroll
        for (int j = 0; j < 8; ++j) hv[j] = (_Float16)tmp[j];
        dbh[ks] = hv;
    }
    const float dbo = decb2[colD];

    float yv0 = z0[(b0 + r) * 3 + 0];
    float yv1 = z0[(b0 + r) * 3 + 1];
    float yv2 = z0[(b0 + r) * 3 + 2];
    float fc0, fc1, fc2;
    float k10, k11, k12, ka0, ka1, ka2, yn0, yn1, yn2;
    float po0 = 0.f, po1 = 0.f, po2 = 0.f;
    float pk0 = 0.f, pk1 = 0.f, pk2 = 0.f;
    float pn0 = 0.f, pn1 = 0.f, pn2 = 0.f;
    float pf0 = 0.f, pf1 = 0.f, pf2 = 0.f;
    int have = 0, pt0 = 0;
    __syncthreads();

// ---- decode chunks (window = 25 points, 200 hd rows, h=0.25, th=0.04q) ----
#define ZCHUNK(T0_)                                                               \
    do {                                                                          \
        for (int ii = (tid & 31); ii < 75; ii += 32) {                            \
            int q = ii / 3, j = ii - q * 3;                                       \
            float ysj = (j == 0) ? po0 : (j == 1) ? po1 : po2;                    \
            float f0j = (j == 0) ? pk0 : (j == 1) ? pk1 : pk2;                    \
            float ynj = (j == 0) ? pn0 : (j == 1) ? pn1 : pn2;                    \
            float fnj = (j == 0) ? pf0 : (j == 1) ? pf1 : pf2;                    \
            float th  = (float)q * 0.04f;                                         \
            float th2 = th * th, th3 = th2 * th;                                  \
            float ca = 2.f * th3 - 3.f * th2 + 1.f;                               \
            float cb = th3 - 2.f * th2 + th;                                      \
            float cc = 3.f * th2 - 2.f * th3;                                     \
            float cd = th3 - th2;                                                 \
            float v = ca * ysj + cb * 0.25f * f0j + cc * ynj + cd * 0.25f * fnj;  \
            traj[((size_t)((T0_) + q) * 4096 + b0 + r) * 3 + j] = v;              \
            zbuf[(q * 8 + r) * 4 + j] = v;                                        \
        }                                                                         \
    } while (0)

#define HCHUNK0                                                                   \
    do {                                                                          \
        const int p  = tid >> 1;                                                  \
        const int u0 = (tid & 1) * 32;                                            \
        const float z0v = zbuf[p * 4 + 0], z1v = zbuf[p * 4 + 1], z2v = zbuf[p * 4 + 2]; \
        const int sw = (p & 7) << 4;                                              \
        _Pragma("unroll")                                                         \
        for (int c = 0; c < 8; ++c) {                                             \
            f16x4 hh_;                                                            \
            _Pragma("unroll")                                                     \
            for (int i = 0; i < 4; ++i) {                                         \
                int u = u0 + c * 4 + i;                                           \
                float acc = b1ds[u] + w1ds[u * 3 + 0] * z0v                       \
                          + w1ds[u * 3 + 1] * z1v + w1ds[u * 3 + 2] * z2v;        \
                hh_[i] = (_Float16)fmaxf(acc, 0.f);                               \
            }                                                                     \
            int off = p * 128 + (((u0 + c * 4) * 2) ^ sw);                        \
            *(f16x4*)(hdc + off) = hh_;                                           \
        }                                                                         \
    } while (0)

#define HCHUNK1                                                                   \
    do {                                                                          \
        const int p  = 128 + (tid >> 2);                                          \
        const int u0 = (tid & 3) * 16;                                            \
        const float z0v = zbuf[p * 4 + 0], z1v = zbuf[p * 4 + 1], z2v = zbuf[p * 4 + 2]; \
        const int sw = (p & 7) << 4;                                              \
        _Pragma("unroll")                                                         \
        for (int c = 0; c < 4; ++c) {                                             \
            f16x4 hh_;                                                            \
            _Pragma("unroll")                                                     \
            for (int i = 0; i < 4; ++i) {                                         \
                int u = u0 + c * 4 + i;                                           \
                float acc = b1ds[u] + w1ds[u * 3 + 0] * z0v                       \
                          + w1ds[u * 3 + 1] * z1v + w1ds[u * 3 + 2] * z2v;        \
                hh_[i] = (_Float16)fmaxf(acc, 0.f);                               \
            }                                                                     \
            int off = p * 128 + (((u0 + c * 4) * 2) ^ sw);                        \
            *(f16x4*)(hdc + off) = hh_;                                           \
        }                                                                         \
    } while (0)

#define HCHUNK2                                                                   \
    do {                                                                          \
        const int p  = 192 + (tid >> 5);                                          \
        const int u0 = (tid & 31) * 2;                                            \
        const float z0v = zbuf[p * 4 + 0], z1v = zbuf[p * 4 + 1], z2v = zbuf[p * 4 + 2]; \
        const int sw = (p & 7) << 4;                                              \
        f16x2 o2;                                                                 \
        _Pragma("unroll")                                                         \
        for (int i = 0; i < 2; ++i) {                                             \
            int u = u0 + i;                                                       \
            float acc = b1ds[u] + w1ds[u * 3 + 0] * z0v                           \
                      + w1ds[u * 3 + 1] * z1v + w1ds[u * 3 + 2] * z2v;            \
            o2[i] = (_Float16)fmaxf(acc, 0.f);                                    \
        }                                                                         \
        *(f16x2*)(hdc + p * 128 + ((u0 * 2) ^ sw)) = o2;                          \
    } while (0)

#define MCHUNKR(LO_, HI_, T0_)                                                    \
    do {                                                                          \
        _Pragma("unroll")                                                         \
        for (int rt = (LO_); rt <= (HI_); ++rt) {                                 \
            int base = (rt * 16 + lrow) * 128;                                    \
            f16x8 a0 = *(const f16x8*)(hdc + base + ((lkb * 16) ^ swA));          \
            f16x8 a1 = *(const f16x8*)(hdc + base + ((64 + lkb * 16) ^ swA));     \
            f32x4 acc = {0.f, 0.f, 0.f, 0.f};                                     \
            acc = MFMA16(a0, dbh[0], acc);                                        \
            acc = MFMA16(a1, dbh[1], acc);                                        \
            _Pragma("unroll")                                                     \
            for (int i = 0; i < 4; ++i) {                                         \
                int pr = rt * 16 + lkb * 4 + i;                                   \
                if (pr < 200) {                                                   \
                    int q2 = pr >> 3, row2 = pr & 7;                              \
                    recon[((size_t)((T0_) + q2) * 4096 + b0 + row2) * 64 + colD] = acc[i] + dbo; \
                }                                                                 \
            }                                                                     \
        }                                                                         \
    } while (0)

#define FEVAL(Y0, Y1, Y2, CH)                                                     \
    do {                                                                          \
        {                                                                         \
            int k0q = (tid & 31) * 4;                                             \
            f16x4 hA;                                                             \
            _Pragma("unroll")                                                     \
            for (int i = 0; i < 4; ++i) {                                         \
                float a_ = b1r[i] + w1r[3 * i] * (Y0)                             \
                         + w1r[3 * i + 1] * (Y1) + w1r[3 * i + 2] * (Y2);         \
                hA[i] = (_Float16)tanh_(a_);                                      \
            }                                                                     \
            *(f16x4*)(h1c + r * 256 + ((k0q * 2) ^ (r << 4))) = hA;               \
        }                                                                         \
        if (have) {                                                               \
            if ((CH) == 1) ZCHUNK(pt0);                                           \
            else if ((CH) == 2) HCHUNK0;                                          \
            else if ((CH) == 3) { HCHUNK1; HCHUNK2; MCHUNKR(0, 5, pt0); }         \
            else if ((CH) == 4) MCHUNKR(6, 12, pt0);                              \
        }                                                                         \
        __syncthreads();                                                          \
        {                                                                         \
            f16x8 ah[4];                                                          \
            _Pragma("unroll")                                                     \
            for (int ks = 0; ks < 4; ++ks)                                        \
                ah[ks] = *(const f16x8*)(h1c + lrow * 256 + ((ks * 64 + lkb * 16) ^ swA)); \
            f32x4 acc0 = {0.f, 0.f, 0.f, 0.f}, acc1 = {0.f, 0.f, 0.f, 0.f};       \
            _Pragma("unroll")                                                     \
            for (int ks = 0; ks < 4; ++ks) {                                      \
                acc0 = MFMA16(ah[ks], w2h[0][ks], acc0);                          \
                acc1 = MFMA16(ah[ks], w2h[1][ks], acc1);                          \
            }                                                                     \
            if (lkb < 2) {                                                        \
                int r0 = lkb * 4;                                                 \
                _Pragma("unroll")                                                 \
                for (int tile = 0; tile < 2; ++tile) {                            \
                    int col = (wv * 2 + tile) * 16 + lrow;                        \
                    f32x4 a = tile ? acc1 : acc0;                                 \
                    if (col < 100) {                                              \
                        float bb = b2s[col];                                      \
                        _Pragma("unroll")                                         \
                        for (int i = 0; i < 4; ++i)                               \
                            h2f[(r0 + i) * 104 + col] = tanh_(a[i] + bb);         \
                    }                                                             \
                }                                                                 \
            }                                                                     \
        }                                                                         \
        __syncthreads();                                                          \
        {                                                                         \
            if (tid < 192) {                                                      \
                int rr = tid / 24, rem = tid - rr * 24, j = rem >> 3, qc = rem & 7;\
                const float4* Wj = (const float4*)(W3s + j * 104);                \
                const float4* Hr = (const float4*)(h2f + rr * 104);               \
                float acc = 0.f;                                                  \
                _Pragma("unroll")                                                 \
                for (int kc = 0; kc < 4; ++kc) {                                  \
                    int k = qc + kc * 8;                                          \
                    if (k < 26) acc += dot4_(Wj[k], Hr[k]);                       \
                }                                                                 \
                acc += __shfl_xor(acc, 1);                                        \
                acc += __shfl_xor(acc, 2);                                        \
                acc += __shfl_xor(acc, 4);                                        \
                if (qc == 0) fparts[rr * 3 + j] = acc + b3s[j];                   \
            }                                                                     \
        }                                                                         \
        __syncthreads();                                                          \
        fc0 = fparts[r * 3 + 0];                                                  \
        fc1 = fparts[r * 3 + 1];                                                  \
        fc2 = fparts[r * 3 + 2];                                                  \
    } while (0)

    FEVAL(yv0, yv1, yv2, 0);

    #pragma unroll 1
    for (int s = 0; s < 8; ++s) {
        const float hh = 0.25f;
        have = (s >= 1);
        pt0  = (s - 1) * 25;

        k10 = fc0; k11 = fc1; k12 = fc2;
        ka0 = fc0; ka1 = fc1; ka2 = fc2;
        float yt0 = yv0 + 0.5f * hh * fc0, yt1 = yv1 + 0.5f * hh * fc1, yt2 = yv2 + 0.5f * hh * fc2;
        FEVAL(yt0, yt1, yt2, 1);                  // k2 + Z(s-1)
        ka0 += 2.f * fc0; ka1 += 2.f * fc1; ka2 += 2.f * fc2;
        yt0 = yv0 + 0.5f * hh * fc0; yt1 = yv1 + 0.5f * hh * fc1; yt2 = yv2 + 0.5f * hh * fc2;
        FEVAL(yt0, yt1, yt2, 2);                  // k3 + H0(s-1)
        ka0 += 2.f * fc0; ka1 += 2.f * fc1; ka2 += 2.f * fc2;
        yt0 = yv0 + hh * fc0; yt1 = yv1 + hh * fc1; yt2 = yv2 + hh * fc2;
        FEVAL(yt0, yt1, yt2, 3);                  // k4 + H1+H2+M0-5(s-1)
        ka0 += fc0; ka1 += fc1; ka2 += fc2;
        const float h6 = hh * (1.f / 6.f);
        yn0 = yv0 + h6 * ka0; yn1 = yv1 + h6 * ka1; yn2 = yv2 + h6 * ka2;
        FEVAL(yn0, yn1, yn2, 4);                  // f(yn) + M6-12(s-1)

        po0 = yv0; po1 = yv1; po2 = yv2;
        pk0 = k10; pk1 = k11; pk2 = k12;
        pn0 = yn0; pn1 = yn1; pn2 = yn2;
        pf0 = fc0; pf1 = fc1; pf2 = fc2;
        yv0 = yn0; yv1 = yn1; yv2 = yn2;
    }

    // epilogue: decode window 7 (t0=175)
    ZCHUNK(175);
    __syncthreads();
    HCHUNK0;
    HCHUNK1;
    HCHUNK2;
    __syncthreads();
    MCHUNKR(0, 12, 175);
#undef FEVAL
#undef ZCHUNK
#undef HCHUNK0
#undef HCHUNK1
#undef HCHUNK2
#undef MCHUNKR
}

extern "C" void kernel_launch(void* const* d_in, const int* in_sizes, int n_in,
                              void* d_out, int out_size, void* d_ws, size_t ws_size,
                              hipStream_t stream)
{
    const float* obs   = (const float*)d_in[0];
    const float* eps   = (const float*)d_in[1];
    const float* Wih   = (const float*)d_in[2];
    const float* Whh   = (const float*)d_in[3];
    const float* bih   = (const float*)d_in[4];
    const float* bhh   = (const float*)d_in[5];
    const float* meanW = (const float*)d_in[6];
    const float* meanB = (const float*)d_in[7];
    const float* lvW   = (const float*)d_in[8];
    const float* lvB   = (const float*)d_in[9];
    const float* dW1   = (const float*)d_in[10];
    const float* db1   = (const float*)d_in[11];
    const float* dW2   = (const float*)d_in[12];
    const float* db2   = (const float*)d_in[13];
    const float* dW3   = (const float*)d_in[14];
    const float* db3   = (const float*)d_in[15];
    const float* decW1 = (const float*)d_in[16];
    const float* decb1 = (const float*)d_in[17];
    const float* decW2 = (const float*)d_in[18];
    const float* decb2 = (const float*)d_in[19];

    float* out   = (float*)d_out;
    float* recon = out;
    float* omean = out + OFF_MEAN;
    float* olv   = out + OFF_LV;
    float* traj  = out + OFF_TRAJ;
    float* z0    = (float*)d_ws;

    k_gru<<<dim3(256), dim3(512), 0, stream>>>(obs, eps, Wih, Whh, bih, bhh,
                                               meanW, meanB, lvW, lvB, omean, olv, z0);
    k_odec<<<dim3(512), dim3(256), 0, stream>>>(dW1, db1, dW2, db2, dW3, db3,
                                                decW1, decb1, decW2, decb2,
                                                z0, traj, recon);
}

// Round 20
// 138.800 us; speedup vs baseline: 1.0151x; 1.0151x over previous
//
#include <hip/hip_runtime.h>
#include <stddef.h>

// Output layout (fp32):
//   recon    [200,4096,64] @ 0
//   z0_mean  [4096,3]      @ 52428800
//   z0_logvar[4096,3]      @ 52441088
//   traj     [200,4096,3]  @ 52453376
#define OFF_MEAN 52428800
#define OFF_LV   52441088
#define OFF_TRAJ 52453376

typedef _Float16 f16x8 __attribute__((ext_vector_type(8)));
typedef _Float16 f16x4 __attribute__((ext_vector_type(4)));
typedef _Float16 f16x2 __attribute__((ext_vector_type(2)));
typedef float    f32x4 __attribute__((ext_vector_type(4)));

#define MFMA16(a, b, c) __builtin_amdgcn_mfma_f32_16x16x32_f16((a), (b), (c), 0, 0, 0)

// fast transcendentals: v_exp_f32 + v_rcp_f32 (error ~1e-6, far below budget)
__device__ __forceinline__ float sigm_(float x) {
    float e = __builtin_amdgcn_exp2f(x * -1.442695041f);
    return __builtin_amdgcn_rcpf(1.f + e);
}
__device__ __forceinline__ float tanh_(float x) {
    float e = __builtin_amdgcn_exp2f(x * 2.885390082f);
    return 1.f - 2.f * __builtin_amdgcn_rcpf(e + 1.f);
}
__device__ __forceinline__ float dot4_(float4 a, float4 b) {
    return a.x * b.x + a.y * b.y + a.z * b.z + a.w * b.w;
}

// ---------------------------------------------------------------- GRU (MFMA, gate-aligned, split chains)
// 256 blocks x 512 threads, 16 rows/block. Accumulator chains split:
// x-side (2-deep) and h-side (4-deep) accumulate independently and add at
// gate time -> critical dependent-MFMA chain 6 -> 4. h-frag reads + h-side
// MFMAs issue first (long poles). Gate uses fused lerp n + zg*(hold-n).
__global__ __launch_bounds__(512, 2) void k_gru(
    const float* __restrict__ obs, const float* __restrict__ eps,
    const float* __restrict__ Wih, const float* __restrict__ Whh,
    const float* __restrict__ bih, const float* __restrict__ bhh,
    const float* __restrict__ meanW, const float* __restrict__ meanB,
    const float* __restrict__ lvW,  const float* __restrict__ lvB,
    float* __restrict__ o_mean, float* __restrict__ o_lv, float* __restrict__ z0)
{
    __shared__ alignas(16) unsigned short h_s[2][2048];  // [16][128] f16, 4-bit swizzle, dbuf
    __shared__ alignas(16) unsigned short x_s[2][1024];  // [16][64]  f16, 3-bit swizzle, dbuf
    __shared__ alignas(16) float hm_s[16 * 132];
    __shared__ float mb_s[96];

    const int tid  = threadIdx.x;
    const int b0   = blockIdx.x * 16;
    const int lane = tid & 63, wv = tid >> 6;
    const int lrow = lane & 15, lkb = lane >> 4;
    const int swX  = (lrow & 7) << 4;
    const int swH  = lrow << 4;
    const int u    = wv * 16 + lrow;

    const float bR  = bih[u]       + bhh[u];
    const float bZ  = bih[128 + u] + bhh[128 + u];
    const float bNi = bih[256 + u];
    const float bNh = bhh[256 + u];

    f16x8 wihf[3][2];
    #pragma unroll
    for (int g = 0; g < 3; ++g) {
        int col = g * 128 + u;
        #pragma unroll
        for (int ks = 0; ks < 2; ++ks) {
            const float* wp = Wih + col * 64 + ks * 32 + lkb * 8;
            float4 a = *(const float4*)wp, b = *(const float4*)(wp + 4);
            float tmp[8] = {a.x, a.y, a.z, a.w, b.x, b.y, b.z, b.w};
            f16x8 hv;
            #pragma unroll
            for (int j = 0; j < 8; ++j) hv[j] = (_Float16)tmp[j];
            wihf[g][ks] = hv;
        }
    }
    f16x8 whhh[3][4];
    #pragma unroll
    for (int g = 0; g < 3; ++g) {
        int col = g * 128 + u;
        #pragma unroll
        for (int ks = 0; ks < 4; ++ks) {
            const float* wp = Whh + col * 128 + ks * 32 + lkb * 8;
            float4 a = *(const float4*)wp, b = *(const float4*)(wp + 4);
            float tmp[8] = {a.x, a.y, a.z, a.w, b.x, b.y, b.z, b.w};
            f16x8 hv;
            #pragma unroll
            for (int j = 0; j < 8; ++j) hv[j] = (_Float16)tmp[j];
            whhh[g][ks] = hv;
        }
    }

    for (int i = tid; i < 2048; i += 512) h_s[0][i] = 0;
    const int srow = tid >> 4, skq = (tid & 15) * 4;
    const int sxb  = srow * 128 + ((skq * 2) ^ ((srow & 7) << 4));
    float4 xn;
    if (tid < 256) {
        xn = *(const float4*)(obs + ((size_t)0 * 4096 + b0 + srow) * 64 + skq);
        f16x4 vh = {(_Float16)xn.x, (_Float16)xn.y, (_Float16)xn.z, (_Float16)xn.w};
        *(f16x4*)((char*)x_s[0] + sxb) = vh;
    }
    f32x4 hold = {0.f, 0.f, 0.f, 0.f};
    __syncthreads();

    for (int t = 0; t < 50; ++t) {
        const int cur = t & 1, nxt = cur ^ 1;
        char* x_c = (char*)x_s[cur];
        char* h_c = (char*)h_s[cur];

        // prefetch x(t+1) (latency hidden under MFMA phase)
        if (tid < 256) {
            int tt = (t < 49) ? t + 1 : t;
            xn = *(const float4*)(obs + ((size_t)tt * 4096 + b0 + srow) * 64 + skq);
        }

        // h A-frags first (feed the 4-deep chains), then x
        f16x8 hh[4], xh[2];
        #pragma unroll
        for (int ks = 0; ks < 4; ++ks) {
            int off = lrow * 256 + ((ks * 64 + lkb * 16) ^ swH);
            hh[ks] = *(const f16x8*)(h_c + off);
        }
        #pragma unroll
        for (int ks = 0; ks < 2; ++ks) {
            int off = lrow * 128 + ((ks * 64 + lkb * 16) ^ swX);
            xh[ks] = *(const f16x8*)(x_c + off);
        }

        f32x4 z4 = {0.f, 0.f, 0.f, 0.f};
        f32x4 aRh = z4, aZh = z4, aNh = z4;   // h-side chains (4-deep)
        f32x4 aRx = z4, aZx = z4, aNi = z4;   // x-side chains (2-deep)
        #pragma unroll
        for (int ks = 0; ks < 4; ++ks) {
            aRh = MFMA16(hh[ks], whhh[0][ks], aRh);
            aZh = MFMA16(hh[ks], whhh[1][ks], aZh);
            aNh = MFMA16(hh[ks], whhh[2][ks], aNh);
        }
        #pragma unroll
        for (int ks = 0; ks < 2; ++ks) {
            aRx = MFMA16(xh[ks], wihf[0][ks], aRx);
            aZx = MFMA16(xh[ks], wihf[1][ks], aZx);
            aNi = MFMA16(xh[ks], wihf[2][ks], aNi);
        }

        char* hn_c = (char*)h_s[nxt];
        #pragma unroll
        for (int i = 0; i < 4; ++i) {
            float rg = sigm_(aRx[i] + aRh[i] + bR);
            float zg = sigm_(aZx[i] + aZh[i] + bZ);
            float n  = tanh_(aNi[i] + bNi + rg * (aNh[i] + bNh));
            float hv = n + zg * (hold[i] - n);
            hold[i] = hv;
            int ri = lkb * 4 + i;
            int hb = ri * 256 + ((u * 2) ^ (ri << 4));
            *(_Float16*)(hn_c + hb) = (_Float16)hv;
        }

        if (tid < 256 && t < 49) {
            f16x4 vh = {(_Float16)xn.x, (_Float16)xn.y, (_Float16)xn.z, (_Float16)xn.w};
            *(f16x4*)((char*)x_s[nxt] + sxb) = vh;
        }
        __syncthreads();
    }

    #pragma unroll
    for (int i = 0; i < 4; ++i)
        hm_s[(lkb * 4 + i) * 132 + u] = hold[i];
    __syncthreads();

    if (tid < 96) {
        int rr = tid / 6, c = tid - rr * 6, j = (c < 3) ? c : c - 3;
        const float* W = (c < 3) ? meanW : lvW;
        const float* B = (c < 3) ? meanB : lvB;
        float acc = B[j];
        const float4* W4 = (const float4*)(W + j * 128);
        const float4* h4 = (const float4*)(hm_s + rr * 132);
        #pragma unroll 4
        for (int kc = 0; kc < 32; ++kc) acc += dot4_(W4[kc], h4[kc]);
        mb_s[rr * 6 + c] = acc;
    }
    __syncthreads();
    if (tid < 48) {
        int rr = tid / 3, j = tid - rr * 3;
        int gb = b0 + rr;
        float m  = mb_s[rr * 6 + j];
        float lv = mb_s[rr * 6 + j + 3];
        o_mean[gb * 3 + j] = m;
        o_lv[gb * 3 + j]   = lv;
        z0[gb * 3 + j]     = m + eps[gb * 3 + j] * __expf(0.5f * lv);
    }
}

// ---------------------------------------------------------------- ODE + decoder (fused, h=0.25 windows)
// (unchanged from round 19)
__global__ __launch_bounds__(256, 2) void k_odec(
    const float* __restrict__ dW1, const float* __restrict__ db1,
    const float* __restrict__ dW2, const float* __restrict__ db2,
    const float* __restrict__ dW3, const float* __restrict__ db3,
    const float* __restrict__ decW1, const float* __restrict__ decb1,
    const float* __restrict__ decW2, const float* __restrict__ decb2,
    const float* __restrict__ z0, float* __restrict__ traj, float* __restrict__ recon)
{
    __shared__ alignas(16) unsigned short h1_s[2048];    // [16][128] f16 swz (rows 8..15 = 0)
    __shared__ alignas(16) unsigned short hd_s[13312];   // [208][64] f16 swz (rows 200-207 pad)
    __shared__ alignas(16) float h2f[8 * 104];
    __shared__ alignas(16) float W3s[312];
    __shared__ alignas(16) float zbuf[200 * 4];
    __shared__ float w1ds[192], b1ds[64];
    __shared__ float b2s[100], b3s[3];
    __shared__ float fparts[24];

    const int tid  = threadIdx.x;
    const int b0   = blockIdx.x * 8;
    const int lane = tid & 63, wv = tid >> 6;
    const int r    = tid >> 5;
    const int lrow = lane & 15, lkb = lane >> 4;
    const int swA  = (lrow & 7) << 4;
    char* h1c = (char*)h1_s;
    char* hdc = (char*)hd_s;

    // init LDS
    for (int i = tid; i < 512; i += 256)
        ((unsigned int*)(h1c + 2048))[i] = 0u;
    for (int i = tid; i < 256; i += 256)
        ((unsigned int*)(hdc + 25600))[i] = 0u;
    if (tid < 32) h2f[(tid >> 2) * 104 + 100 + (tid & 3)] = 0.f;
    for (int i = tid; i < 312; i += 256) {
        int j = i / 104, k = i - j * 104;
        W3s[i] = (k < 100) ? dW3[j * 100 + k] : 0.f;
    }
    if (tid < 100) b2s[tid] = db2[tid];
    if (tid < 3)   b3s[tid] = db3[tid];
    if (tid < 192) w1ds[tid] = decW1[tid];
    if (tid < 64)  b1ds[tid] = decb1[tid];

    float w1r[12], b1r[4];
    {
        int k0q = (tid & 31) * 4;
        #pragma unroll
        for (int i = 0; i < 4; ++i) {
            int k = k0q + i;
            if (k < 100) {
                w1r[3 * i + 0] = dW1[k * 3 + 0];
                w1r[3 * i + 1] = dW1[k * 3 + 1];
                w1r[3 * i + 2] = dW1[k * 3 + 2];
                b1r[i] = db1[k];
            } else {
                w1r[3 * i + 0] = 0.f; w1r[3 * i + 1] = 0.f; w1r[3 * i + 2] = 0.f;
                b1r[i] = 0.f;
            }
        }
    }
    f16x8 w2h[2][4];
    #pragma unroll
    for (int tile = 0; tile < 2; ++tile) {
        int col = (wv * 2 + tile) * 16 + lrow;
        #pragma unroll
        for (int ks = 0; ks < 4; ++ks) {
            f16x8 hv;
            #pragma unroll
            for (int j = 0; j < 8; ++j) {
                int k = ks * 32 + lkb * 8 + j;
                float v = (col < 100 && k < 100) ? dW2[col * 100 + k] : 0.f;
                hv[j] = (_Float16)v;
            }
            w2h[tile][ks] = hv;
        }
    }
    const int colD = wv * 16 + lrow;
    f16x8 dbh[2];
    #pragma unroll
    for (int ks = 0; ks < 2; ++ks) {
        const float* wp = decW2 + colD * 64 + ks * 32 + lkb * 8;
        float4 a = *(const float4*)wp, b = *(const float4*)(wp + 4);
        float tmp[8] = {a.x, a.y, a.z, a.w, b.x, b.y, b.z, b.w};
        f16x8 hv;
        #pragma unroll
        for (int j = 0; j < 8; ++j) hv[j] = (_Float16)tmp[j];
        dbh[ks] = hv;
    }
    const float dbo = decb2[colD];

    float yv0 = z0[(b0 + r) * 3 + 0];
    float yv1 = z0[(b0 + r) * 3 + 1];
    float yv2 = z0[(b0 + r) * 3 + 2];
    float fc0, fc1, fc2;
    float k10, k11, k12, ka0, ka1, ka2, yn0, yn1, yn2;
    float po0 = 0.f, po1 = 0.f, po2 = 0.f;
    float pk0 = 0.f, pk1 = 0.f, pk2 = 0.f;
    float pn0 = 0.f, pn1 = 0.f, pn2 = 0.f;
    float pf0 = 0.f, pf1 = 0.f, pf2 = 0.f;
    int have = 0, pt0 = 0;
    __syncthreads();

#define ZCHUNK(T0_)                                                               \
    do {                                                                          \
        for (int ii = (tid & 31); ii < 75; ii += 32) {                            \
            int q = ii / 3, j = ii - q * 3;                                       \
            float ysj = (j == 0) ? po0 : (j == 1) ? po1 : po2;                    \
            float f0j = (j == 0) ? pk0 : (j == 1) ? pk1 : pk2;                    \
            float ynj = (j == 0) ? pn0 : (j == 1) ? pn1 : pn2;                    \
            float fnj = (j == 0) ? pf0 : (j == 1) ? pf1 : pf2;                    \
            float th  = (float)q * 0.04f;                                         \
            float th2 = th * th, th3 = th2 * th;                                  \
            float ca = 2.f * th3 - 3.f * th2 + 1.f;                               \
            float cb = th3 - 2.f * th2 + th;                                      \
            float cc = 3.f * th2 - 2.f * th3;                                     \
            float cd = th3 - th2;                                                 \
            float v = ca * ysj + cb * 0.25f * f0j + cc * ynj + cd * 0.25f * fnj;  \
            traj[((size_t)((T0_) + q) * 4096 + b0 + r) * 3 + j] = v;              \
            zbuf[(q * 8 + r) * 4 + j] = v;                                        \
        }                                                                         \
    } while (0)

#define HCHUNK0                                                                   \
    do {                                                                          \
        const int p  = tid >> 1;                                                  \
        const int u0 = (tid & 1) * 32;                                            \
        const float z0v = zbuf[p * 4 + 0], z1v = zbuf[p * 4 + 1], z2v = zbuf[p * 4 + 2]; \
        const int sw = (p & 7) << 4;                                              \
        _Pragma("unroll")                                                         \
        for (int c = 0; c < 8; ++c) {                                             \
            f16x4 hh_;                                                            \
            _Pragma("unroll")                                                     \
            for (int i = 0; i < 4; ++i) {                                         \
                int u = u0 + c * 4 + i;                                           \
                float acc = b1ds[u] + w1ds[u * 3 + 0] * z0v                       \
                          + w1ds[u * 3 + 1] * z1v + w1ds[u * 3 + 2] * z2v;        \
                hh_[i] = (_Float16)fmaxf(acc, 0.f);                               \
            }                                                                     \
            int off = p * 128 + (((u0 + c * 4) * 2) ^ sw);                        \
            *(f16x4*)(hdc + off) = hh_;                                           \
        }                                                                         \
    } while (0)

#define HCHUNK1                                                                   \
    do {                                                                          \
        const int p  = 128 + (tid >> 2);                                          \
        const int u0 = (tid & 3) * 16;                                            \
        const float z0v = zbuf[p * 4 + 0], z1v = zbuf[p * 4 + 1], z2v = zbuf[p * 4 + 2]; \
        const int sw = (p & 7) << 4;                                              \
        _Pragma("unroll")                                                         \
        for (int c = 0; c < 4; ++c) {                                             \
            f16x4 hh_;                                                            \
            _Pragma("unroll")                                                     \
            for (int i = 0; i < 4; ++i) {                                         \
                int u = u0 + c * 4 + i;                                           \
                float acc = b1ds[u] + w1ds[u * 3 + 0] * z0v                       \
                          + w1ds[u * 3 + 1] * z1v + w1ds[u * 3 + 2] * z2v;        \
                hh_[i] = (_Float16)fmaxf(acc, 0.f);                               \
            }                                                                     \
            int off = p * 128 + (((u0 + c * 4) * 2) ^ sw);                        \
            *(f16x4*)(hdc + off) = hh_;                                           \
        }                                                                         \
    } while (0)

#define HCHUNK2                                                                   \
    do {                                                                          \
        const int p  = 192 + (tid >> 5);                                          \
        const int u0 = (tid & 31) * 2;                                            \
        const float z0v = zbuf[p * 4 + 0], z1v = zbuf[p * 4 + 1], z2v = zbuf[p * 4 + 2]; \
        const int sw = (p & 7) << 4;                                              \
        f16x2 o2;                                                                 \
        _Pragma("unroll")                                                         \
        for (int i = 0; i < 2; ++i) {                                             \
            int u = u0 + i;                                                       \
            float acc = b1ds[u] + w1ds[u * 3 + 0] * z0v                           \
                      + w1ds[u * 3 + 1] * z1v + w1ds[u * 3 + 2] * z2v;            \
            o2[i] = (_Float16)fmaxf(acc, 0.f);                                    \
        }                                                                         \
        *(f16x2*)(hdc + p * 128 + ((u0 * 2) ^ sw)) = o2;                          \
    } while (0)

#define MCHUNKR(LO_, HI_, T0_)                                                    \
    do {                                                                          \
        _Pragma("unroll")                                                         \
        for (int rt = (LO_); rt <= (HI_); ++rt) {                                 \
            int base = (rt * 16 + lrow) * 128;                                    \
            f16x8 a0 = *(const f16x8*)(hdc + base + ((lkb * 16) ^ swA));          \
            f16x8 a1 = *(const f16x8*)(hdc + base + ((64 + lkb * 16) ^ swA));     \
            f32x4 acc = {0.f, 0.f, 0.f, 0.f};                                     \
            acc = MFMA16(a0, dbh[0], acc);                                        \
            acc = MFMA16(a1, dbh[1], acc);                                        \
            _Pragma("unroll")                                                     \
            for (int i = 0; i < 4; ++i) {                                         \
                int pr = rt * 16 + lkb * 4 + i;                                   \
                if (pr < 200) {                                                   \
                    int q2 = pr >> 3, row2 = pr & 7;                              \
                    recon[((size_t)((T0_) + q2) * 4096 + b0 + row2) * 64 + colD] = acc[i] + dbo; \
                }                                                                 \
            }                                                                     \
        }                                                                         \
    } while (0)

#define FEVAL(Y0, Y1, Y2, CH)                                                     \
    do {                                                                          \
        {                                                                         \
            int k0q = (tid & 31) * 4;                                             \
            f16x4 hA;                                                             \
            _Pragma("unroll")                                                     \
            for (int i = 0; i < 4; ++i) {                                         \
                float a_ = b1r[i] + w1r[3 * i] * (Y0)                             \
                         + w1r[3 * i + 1] * (Y1) + w1r[3 * i + 2] * (Y2);         \
                hA[i] = (_Float16)tanh_(a_);                                      \
            }                                                                     \
            *(f16x4*)(h1c + r * 256 + ((k0q * 2) ^ (r << 4))) = hA;               \
        }                                                                         \
        if (have) {                                                               \
            if ((CH) == 1) ZCHUNK(pt0);                                           \
            else if ((CH) == 2) HCHUNK0;                                          \
            else if ((CH) == 3) { HCHUNK1; HCHUNK2; MCHUNKR(0, 5, pt0); }         \
            else if ((CH) == 4) MCHUNKR(6, 12, pt0);                              \
        }                                                                         \
        __syncthreads();                                                          \
        {                                                                         \
            f16x8 ah[4];                                                          \
            _Pragma("unroll")                                                     \
            for (int ks = 0; ks < 4; ++ks)                                        \
                ah[ks] = *(const f16x8*)(h1c + lrow * 256 + ((ks * 64 + lkb * 16) ^ swA)); \
            f32x4 acc0 = {0.f, 0.f, 0.f, 0.f}, acc1 = {0.f, 0.f, 0.f, 0.f};       \
            _Pragma("unroll")                                                     \
            for (int ks = 0; ks < 4; ++ks) {                                      \
                acc0 = MFMA16(ah[ks], w2h[0][ks], acc0);                          \
                acc1 = MFMA16(ah[ks], w2h[1][ks], acc1);                          \
            }                                                                     \
            if (lkb < 2) {                                                        \
                int r0 = lkb * 4;                                                 \
                _Pragma("unroll")                                                 \
                for (int tile = 0; tile < 2; ++tile) {                            \
                    int col = (wv * 2 + tile) * 16 + lrow;                        \
                    f32x4 a = tile ? acc1 : acc0;                                 \
                    if (col < 100) {                                              \
                        float bb = b2s[col];                                      \
                        _Pragma("unroll")                                         \
                        for (int i = 0; i < 4; ++i)                               \
                            h2f[(r0 + i) * 104 + col] = tanh_(a[i] + bb);         \
                    }                                                             \
                }                                                                 \
            }                                                                     \
        }                                                                         \
        __syncthreads();                                                          \
        {                                                                         \
            if (tid < 192) {                                                      \
                int rr = tid / 24, rem = tid - rr * 24, j = rem >> 3, qc = rem & 7;\
                const float4* Wj = (const float4*)(W3s + j * 104);                \
                const float4* Hr = (const float4*)(h2f + rr * 104);               \
                float acc = 0.f;                                                  \
                _Pragma("unroll")                                                 \
                for (int kc = 0; kc < 4; ++kc) {                                  \
                    int k = qc + kc * 8;                                          \
                    if (k < 26) acc += dot4_(Wj[k], Hr[k]);                       \
                }                                                                 \
                acc += __shfl_xor(acc, 1);                                        \
                acc += __shfl_xor(acc, 2);                                        \
                acc += __shfl_xor(acc, 4);                                        \
                if (qc == 0) fparts[rr * 3 + j] = acc + b3s[j];                   \
            }                                                                     \
        }                                                                         \
        __syncthreads();                                                          \
        fc0 = fparts[r * 3 + 0];                                                  \
        fc1 = fparts[r * 3 + 1];                                                  \
        fc2 = fparts[r * 3 + 2];                                                  \
    } while (0)

    FEVAL(yv0, yv1, yv2, 0);

    #pragma unroll 1
    for (int s = 0; s < 8; ++s) {
        const float hh = 0.25f;
        have = (s >= 1);
        pt0  = (s - 1) * 25;

        k10 = fc0; k11 = fc1; k12 = fc2;
        ka0 = fc0; ka1 = fc1; ka2 = fc2;
        float yt0 = yv0 + 0.5f * hh * fc0, yt1 = yv1 + 0.5f * hh * fc1, yt2 = yv2 + 0.5f * hh * fc2;
        FEVAL(yt0, yt1, yt2, 1);                  // k2 + Z(s-1)
        ka0 += 2.f * fc0; ka1 += 2.f * fc1; ka2 += 2.f * fc2;
        yt0 = yv0 + 0.5f * hh * fc0; yt1 = yv1 + 0.5f * hh * fc1; yt2 = yv2 + 0.5f * hh * fc2;
        FEVAL(yt0, yt1, yt2, 2);                  // k3 + H0(s-1)
        ka0 += 2.f * fc0; ka1 += 2.f * fc1; ka2 += 2.f * fc2;
        yt0 = yv0 + hh * fc0; yt1 = yv1 + hh * fc1; yt2 = yv2 + hh * fc2;
        FEVAL(yt0, yt1, yt2, 3);                  // k4 + H1+H2+M0-5(s-1)
        ka0 += fc0; ka1 += fc1; ka2 += fc2;
        const float h6 = hh * (1.f / 6.f);
        yn0 = yv0 + h6 * ka0; yn1 = yv1 + h6 * ka1; yn2 = yv2 + h6 * ka2;
        FEVAL(yn0, yn1, yn2, 4);                  // f(yn) + M6-12(s-1)

        po0 = yv0; po1 = yv1; po2 = yv2;
        pk0 = k10; pk1 = k11; pk2 = k12;
        pn0 = yn0; pn1 = yn1; pn2 = yn2;
        pf0 = fc0; pf1 = fc1; pf2 = fc2;
        yv0 = yn0; yv1 = yn1; yv2 = yn2;
    }

    // epilogue: decode window 7 (t0=175)
    ZCHUNK(175);
    __syncthreads();
    HCHUNK0;
    HCHUNK1;
    HCHUNK2;
    __syncthreads();
    MCHUNKR(0, 12, 175);
#undef FEVAL
#undef ZCHUNK
#undef HCHUNK0
#undef HCHUNK1
#undef HCHUNK2
#undef MCHUNKR
}

extern "C" void kernel_launch(void* const* d_in, const int* in_sizes, int n_in,
                              void* d_out, int out_size, void* d_ws, size_t ws_size,
                              hipStream_t stream)
{
    const float* obs   = (const float*)d_in[0];
    const float* eps   = (const float*)d_in[1];
    const float* Wih   = (const float*)d_in[2];
    const float* Whh   = (const float*)d_in[3];
    const float* bih   = (const float*)d_in[4];
    const float* bhh   = (const float*)d_in[5];
    const float* meanW = (const float*)d_in[6];
    const float* meanB = (const float*)d_in[7];
    const float* lvW   = (const float*)d_in[8];
    const float* lvB   = (const float*)d_in[9];
    const float* dW1   = (const float*)d_in[10];
    const float* db1   = (const float*)d_in[11];
    const float* dW2   = (const float*)d_in[12];
    const float* db2   = (const float*)d_in[13];
    const float* dW3   = (const float*)d_in[14];
    const float* db3   = (const float*)d_in[15];
    const float* decW1 = (const float*)d_in[16];
    const float* decb1 = (const float*)d_in[17];
    const float* decW2 = (const float*)d_in[18];
    const float* decb2 = (const float*)d_in[19];

    float* out   = (float*)d_out;
    float* recon = out;
    float* omean = out + OFF_MEAN;
    float* olv   = out + OFF_LV;
    float* traj  = out + OFF_TRAJ;
    float* z0    = (float*)d_ws;

    k_gru<<<dim3(256), dim3(512), 0, stream>>>(obs, eps, Wih, Whh, bih, bhh,
                                               meanW, meanB, lvW, lvB, omean, olv, z0);
    k_odec<<<dim3(512), dim3(256), 0, stream>>>(dW1, db1, dW2, db2, dW3, db3,
                                                decW1, decb1, decW2, decb2,
                                                z0, traj, recon);
}